// Round 1
// 788.631 us; speedup vs baseline: 1.2278x; 1.2278x over previous
//
#include <hip/hip_runtime.h>
#include <hip/hip_bf16.h>

#define BH 128
#define SEQ 1024
#define DH 64
#define MT 16          // query rows per block
#define NW 256         // keys per wave
#define PSTRIDE 1032   // P_lds row stride in shorts (padded +8 to break bank conflicts)

typedef __attribute__((ext_vector_type(8))) short short8;
typedef __attribute__((ext_vector_type(4))) float float4v;

__device__ __forceinline__ short bf16_rne(float x) {
    unsigned u = __builtin_bit_cast(unsigned, x);
    unsigned r = (u + 0x7fffu + ((u >> 16) & 1u)) >> 16;
    return (short)r;
}

// hi = truncated bf16, lo = RNE bf16 of the residual (x ~= hi + lo to ~2^-17 rel)
__device__ __forceinline__ void bf16_split(float x, short& hi, short& lo) {
    unsigned u = __builtin_bit_cast(unsigned, x);
    hi = (short)(u >> 16);
    float hf = __builtin_bit_cast(float, u & 0xffff0000u);
    float res = x - hf;
    unsigned v = __builtin_bit_cast(unsigned, res);
    lo = (short)((v + 0x7fffu + ((v >> 16) & 1u)) >> 16);
}

// ---------------------------------------------------------------------------
// Pre-pass: convert K -> (Khi, Klo) split bf16 and V -> Vt bf16, both stored
// in MFMA B-fragment order so the main kernel does pure 16B vector loads.
//
// Khi/Klo element (key, d) of head bh stored at:
//   bh*65536 + ((keyblk*2 + s)*16 + l)*32 + q*8 + j
//   where keyblk=key/16, l=key%16, s=d/32, q=(d%32)/8, j=d%8
// Vt element (d, key) of head bh stored at:
//   bh*65536 + ((d4*128 + key8)*16 + lv)*8 + j
//   where d4=d/16, lv=d%16, key8=key/8, j=key%8
// ---------------------------------------------------------------------------
__global__ __launch_bounds__(256, 4)
void attn_convert_kernel(const float* __restrict__ K, const float* __restrict__ V,
                         short* __restrict__ Khi, short* __restrict__ Klo,
                         short* __restrict__ Vt)
{
    const unsigned c = blockIdx.x * 256u + threadIdx.x;   // chunk of 8 shorts
    if (blockIdx.x < 4096) {
        // ---- K: 128 bh * 8192 chunks ----
        const int bh = c >> 13;
        const int o8 = c & 8191;
        const int q  = o8 & 3;
        const int l  = (o8 >> 2) & 15;
        const int s  = (o8 >> 6) & 1;
        const int kb = o8 >> 7;
        const float* src = K + ((size_t)bh * SEQ + kb * 16 + l) * DH + s * 32 + q * 8;
        float4v x0 = *(const float4v*)src;
        float4v x1 = *(const float4v*)(src + 4);
        short8 hi, lo;
        #pragma unroll
        for (int j = 0; j < 4; ++j) {
            short h, w;
            bf16_split(x0[j], h, w); hi[j] = h;     lo[j] = w;
            bf16_split(x1[j], h, w); hi[4 + j] = h; lo[4 + j] = w;
        }
        *(short8*)(Khi + (size_t)c * 8) = hi;
        *(short8*)(Klo + (size_t)c * 8) = lo;
    } else {
        // ---- V: 128 bh * 8192 chunks ----
        const unsigned c2 = c - 4096u * 256u;
        const int bh = c2 >> 13;
        const int o8 = c2 & 8191;
        const int lv = o8 & 15;
        const int k8 = (o8 >> 4) & 127;
        const int d4 = o8 >> 11;
        const float* src = V + ((size_t)bh * SEQ + k8 * 8) * DH + d4 * 16 + lv;
        short8 vv;
        #pragma unroll
        for (int j = 0; j < 8; ++j) vv[j] = bf16_rne(src[(size_t)j * DH]);
        *(short8*)(Vt + (size_t)c2 * 8) = vv;
    }
}

// ---------------------------------------------------------------------------
// Main attention kernel: consumes pre-swizzled bf16 K (split) and V.
// ---------------------------------------------------------------------------
__global__ __launch_bounds__(256, 3)
void Attention_66889820668421_kernel(const float* __restrict__ Q,
                                     const short* __restrict__ Khi,
                                     const short* __restrict__ Klo,
                                     const short* __restrict__ Vt,
                                     const int*   __restrict__ mask,
                                     float* __restrict__ out,
                                     float* __restrict__ pattn)
{
    __shared__ short P_lds[MT * PSTRIDE];          // 33 KB: p tile, bf16
    __shared__ float out_red[4][MT][DH];           // 16 KB: per-wave partial PV
    __shared__ float red_max[4][MT];
    __shared__ float red_sum[4][MT];

    const int tid  = threadIdx.x;
    const int wave = tid >> 6;
    const int lane = tid & 63;
    const int q    = lane >> 4;     // quad 0..3
    const int l    = lane & 15;
    const int bh   = blockIdx.y;
    const int m0   = blockIdx.x * MT;
    const int nbase = wave * NW;

    // ---------------- Q fragments (split hi/lo), 2 K-steps of 32 ----------------
    short8 a_hi[2], a_lo[2];
    {
        const float* qrow = Q + (size_t)(bh * SEQ + m0 + l) * DH;
        #pragma unroll
        for (int s = 0; s < 2; ++s) {
            float4v x0 = *(const float4v*)(qrow + s * 32 + q * 8);
            float4v x1 = *(const float4v*)(qrow + s * 32 + q * 8 + 4);
            #pragma unroll
            for (int j = 0; j < 4; ++j) {
                short h, lo2;
                bf16_split(x0[j], h, lo2); a_hi[s][j] = h; a_lo[s][j] = lo2;
                bf16_split(x1[j], h, lo2); a_hi[s][4 + j] = h; a_lo[s][4 + j] = lo2;
            }
        }
    }

    const short* khb = Khi + ((size_t)bh << 16);
    const short* klb = Klo + ((size_t)bh << 16);
    const short* vtb = Vt  + ((size_t)bh << 16);

    // ---------------- QK^T: 16 tiles of 16 keys, split-precision MFMA ------------
    float4v acc[16];
    int mv[16];
    #pragma unroll
    for (int t = 0; t < 16; ++t) {
        const int kb   = (nbase >> 4) + t;
        const int off0 = kb * 1024 + l * 32 + q * 8;   // s=0 fragment
        short8 b0h = *(const short8*)(khb + off0);
        short8 b0l = *(const short8*)(klb + off0);
        short8 b1h = *(const short8*)(khb + off0 + 512);
        short8 b1l = *(const short8*)(klb + off0 + 512);
        float4v a = {0.f, 0.f, 0.f, 0.f};
        a = __builtin_amdgcn_mfma_f32_16x16x32_bf16(a_hi[0], b0h, a, 0, 0, 0);
        a = __builtin_amdgcn_mfma_f32_16x16x32_bf16(a_hi[0], b0l, a, 0, 0, 0);
        a = __builtin_amdgcn_mfma_f32_16x16x32_bf16(a_lo[0], b0h, a, 0, 0, 0);
        a = __builtin_amdgcn_mfma_f32_16x16x32_bf16(a_hi[1], b1h, a, 0, 0, 0);
        a = __builtin_amdgcn_mfma_f32_16x16x32_bf16(a_hi[1], b1l, a, 0, 0, 0);
        a = __builtin_amdgcn_mfma_f32_16x16x32_bf16(a_lo[1], b1h, a, 0, 0, 0);
        mv[t] = mask[bh * SEQ + nbase + t * 16 + l];
        acc[t] = a;
    }

    // ---------------- scale + mask + row max ----------------
    const float scale = 0.03125f;   // 1/sqrt(1024)
    float pm[4] = {-3e38f, -3e38f, -3e38f, -3e38f};
    #pragma unroll
    for (int t = 0; t < 16; ++t) {
        const bool ok = (mv[t] != 0);
        #pragma unroll
        for (int r = 0; r < 4; ++r) {
            float s = ok ? acc[t][r] * scale : -1e9f;
            acc[t][r] = s;
            pm[r] = fmaxf(pm[r], s);
        }
    }
    #pragma unroll
    for (int off = 1; off < 16; off <<= 1) {
        #pragma unroll
        for (int r = 0; r < 4; ++r)
            pm[r] = fmaxf(pm[r], __shfl_xor(pm[r], off));
    }
    if (l == 0) {
        #pragma unroll
        for (int r = 0; r < 4; ++r) red_max[wave][q * 4 + r] = pm[r];
    }
    __syncthreads();

    float rm[4];
    #pragma unroll
    for (int r = 0; r < 4; ++r) {
        const int row = q * 4 + r;
        rm[r] = fmaxf(fmaxf(red_max[0][row], red_max[1][row]),
                      fmaxf(red_max[2][row], red_max[3][row]));
    }

    // ---------------- exp + row sum ----------------
    float ps[4] = {0.f, 0.f, 0.f, 0.f};
    #pragma unroll
    for (int t = 0; t < 16; ++t) {
        #pragma unroll
        for (int r = 0; r < 4; ++r) {
            float e = __expf(acc[t][r] - rm[r]);
            acc[t][r] = e;
            ps[r] += e;
        }
    }
    #pragma unroll
    for (int off = 1; off < 16; off <<= 1) {
        #pragma unroll
        for (int r = 0; r < 4; ++r)
            ps[r] += __shfl_xor(ps[r], off);
    }
    if (l == 0) {
        #pragma unroll
        for (int r = 0; r < 4; ++r) red_sum[wave][q * 4 + r] = ps[r];
    }
    __syncthreads();

    float inv[4];
    #pragma unroll
    for (int r = 0; r < 4; ++r) {
        const int row = q * 4 + r;
        inv[r] = 1.0f / (red_sum[0][row] + red_sum[1][row] +
                         red_sum[2][row] + red_sum[3][row]);
    }

    // ---------------- normalize, write p (fp32 global, streaming) + P_lds -------
    float* prow = pattn + ((size_t)bh * SEQ + m0) * SEQ;
    #pragma unroll
    for (int t = 0; t < 16; ++t) {
        const int col = nbase + t * 16 + l;
        #pragma unroll
        for (int r = 0; r < 4; ++r) {
            const int row = q * 4 + r;
            float p = acc[t][r] * inv[r];
            __builtin_nontemporal_store(p, &prow[(size_t)row * SEQ + col]);
            P_lds[row * PSTRIDE + col] = bf16_rne(p);
        }
    }
    __syncthreads();

    // ---------------- PV: each wave multiplies its 256-key chunk -----------------
    float4v ao[4];
    #pragma unroll
    for (int dt = 0; dt < 4; ++dt) ao[dt] = (float4v){0.f, 0.f, 0.f, 0.f};

    #pragma unroll
    for (int step = 0; step < 8; ++step) {
        const int key0 = nbase + step * 32;
        short8 pa = *(const short8*)&P_lds[l * PSTRIDE + key0 + q * 8];
        const int k8q = (key0 >> 3) + q;
        #pragma unroll
        for (int dt = 0; dt < 4; ++dt) {
            short8 vb = *(const short8*)(vtb + ((size_t)(dt * 128 + k8q) * 16 + l) * 8);
            ao[dt] = __builtin_amdgcn_mfma_f32_16x16x32_bf16(pa, vb, ao[dt], 0, 0, 0);
        }
    }

    // ---------------- cross-wave reduce + store out ------------------------------
    #pragma unroll
    for (int dt = 0; dt < 4; ++dt) {
        #pragma unroll
        for (int r = 0; r < 4; ++r)
            out_red[wave][q * 4 + r][dt * 16 + l] = ao[dt][r];
    }
    __syncthreads();

    #pragma unroll
    for (int i = 0; i < 4; ++i) {
        const int e = tid + 256 * i;
        const int row = e >> 6;
        const int d = e & 63;
        float s = out_red[0][row][d] + out_red[1][row][d] +
                  out_red[2][row][d] + out_red[3][row][d];
        __builtin_nontemporal_store(s, &out[(size_t)(bh * SEQ + m0 + row) * DH + d]);
    }
}

// ---------------------------------------------------------------------------
// Fallback (previous session's kernel, unchanged) — used if ws too small.
// ---------------------------------------------------------------------------
__global__ __launch_bounds__(256, 2)
void Attention_66889820668421_fallback(const float* __restrict__ Q,
                                       const float* __restrict__ K,
                                       const float* __restrict__ V,
                                       const int*   __restrict__ mask,
                                       float* __restrict__ out,
                                       float* __restrict__ pattn)
{
    __shared__ short P_lds[MT * PSTRIDE];
    __shared__ float out_red[4][MT][DH];
    __shared__ float red_max[4][MT];
    __shared__ float red_sum[4][MT];

    const int tid  = threadIdx.x;
    const int wave = tid >> 6;
    const int lane = tid & 63;
    const int q    = lane >> 4;
    const int l    = lane & 15;
    const int bh   = blockIdx.y;
    const int m0   = blockIdx.x * MT;
    const int nbase = wave * NW;

    short8 a_hi[2], a_lo[2];
    {
        const float* qrow = Q + (size_t)(bh * SEQ + m0 + l) * DH;
        #pragma unroll
        for (int s = 0; s < 2; ++s) {
            float4v x0 = *(const float4v*)(qrow + s * 32 + q * 8);
            float4v x1 = *(const float4v*)(qrow + s * 32 + q * 8 + 4);
            #pragma unroll
            for (int j = 0; j < 4; ++j) {
                short h, lo2;
                bf16_split(x0[j], h, lo2); a_hi[s][j] = h; a_lo[s][j] = lo2;
                bf16_split(x1[j], h, lo2); a_hi[s][4 + j] = h; a_lo[s][4 + j] = lo2;
            }
        }
    }

    float4v acc[16];
    int mv[16];
    #pragma unroll
    for (int t = 0; t < 16; ++t) {
        const int key = nbase + t * 16 + l;
        const float* krow = K + (size_t)(bh * SEQ + key) * DH;
        float4v a = {0.f, 0.f, 0.f, 0.f};
        #pragma unroll
        for (int s = 0; s < 2; ++s) {
            float4v x0 = *(const float4v*)(krow + s * 32 + q * 8);
            float4v x1 = *(const float4v*)(krow + s * 32 + q * 8 + 4);
            short8 bhh, bll;
            #pragma unroll
            for (int j = 0; j < 4; ++j) {
                short h, lo2;
                bf16_split(x0[j], h, lo2); bhh[j] = h; bll[j] = lo2;
                bf16_split(x1[j], h, lo2); bhh[4 + j] = h; bll[4 + j] = lo2;
            }
            a = __builtin_amdgcn_mfma_f32_16x16x32_bf16(a_hi[s], bhh, a, 0, 0, 0);
            a = __builtin_amdgcn_mfma_f32_16x16x32_bf16(a_hi[s], bll, a, 0, 0, 0);
            a = __builtin_amdgcn_mfma_f32_16x16x32_bf16(a_lo[s], bhh, a, 0, 0, 0);
        }
        mv[t] = mask[bh * SEQ + nbase + t * 16 + l];
        acc[t] = a;
    }

    const float scale = 0.03125f;
    float pm[4] = {-3e38f, -3e38f, -3e38f, -3e38f};
    #pragma unroll
    for (int t = 0; t < 16; ++t) {
        const bool ok = (mv[t] != 0);
        #pragma unroll
        for (int r = 0; r < 4; ++r) {
            float s = ok ? acc[t][r] * scale : -1e9f;
            acc[t][r] = s;
            pm[r] = fmaxf(pm[r], s);
        }
    }
    #pragma unroll
    for (int off = 1; off < 16; off <<= 1) {
        #pragma unroll
        for (int r = 0; r < 4; ++r)
            pm[r] = fmaxf(pm[r], __shfl_xor(pm[r], off));
    }
    if (l == 0) {
        #pragma unroll
        for (int r = 0; r < 4; ++r) red_max[wave][q * 4 + r] = pm[r];
    }
    __syncthreads();

    float rm[4];
    #pragma unroll
    for (int r = 0; r < 4; ++r) {
        const int row = q * 4 + r;
        rm[r] = fmaxf(fmaxf(red_max[0][row], red_max[1][row]),
                      fmaxf(red_max[2][row], red_max[3][row]));
    }

    float ps[4] = {0.f, 0.f, 0.f, 0.f};
    #pragma unroll
    for (int t = 0; t < 16; ++t) {
        #pragma unroll
        for (int r = 0; r < 4; ++r) {
            float e = __expf(acc[t][r] - rm[r]);
            acc[t][r] = e;
            ps[r] += e;
        }
    }
    #pragma unroll
    for (int off = 1; off < 16; off <<= 1) {
        #pragma unroll
        for (int r = 0; r < 4; ++r)
            ps[r] += __shfl_xor(ps[r], off);
    }
    if (l == 0) {
        #pragma unroll
        for (int r = 0; r < 4; ++r) red_sum[wave][q * 4 + r] = ps[r];
    }
    __syncthreads();

    float inv[4];
    #pragma unroll
    for (int r = 0; r < 4; ++r) {
        const int row = q * 4 + r;
        inv[r] = 1.0f / (red_sum[0][row] + red_sum[1][row] +
                         red_sum[2][row] + red_sum[3][row]);
    }

    float* prow = pattn + ((size_t)bh * SEQ + m0) * SEQ;
    #pragma unroll
    for (int t = 0; t < 16; ++t) {
        const int col = nbase + t * 16 + l;
        #pragma unroll
        for (int r = 0; r < 4; ++r) {
            const int row = q * 4 + r;
            float p = acc[t][r] * inv[r];
            prow[(size_t)row * SEQ + col] = p;
            P_lds[row * PSTRIDE + col] = bf16_rne(p);
        }
    }
    __syncthreads();

    float4v ao[4];
    #pragma unroll
    for (int dt = 0; dt < 4; ++dt) ao[dt] = (float4v){0.f, 0.f, 0.f, 0.f};

    #pragma unroll 2
    for (int step = 0; step < 8; ++step) {
        const int key0 = nbase + step * 32;
        short8 pa = *(const short8*)&P_lds[l * PSTRIDE + key0 + q * 8];
        const float* vbase = V + (size_t)(bh * SEQ + key0 + q * 8) * DH + l;
        #pragma unroll
        for (int dt = 0; dt < 4; ++dt) {
            short8 vb;
            #pragma unroll
            for (int j = 0; j < 8; ++j)
                vb[j] = bf16_rne(vbase[(size_t)j * DH + dt * 16]);
            ao[dt] = __builtin_amdgcn_mfma_f32_16x16x32_bf16(pa, vb, ao[dt], 0, 0, 0);
        }
    }

    #pragma unroll
    for (int dt = 0; dt < 4; ++dt) {
        #pragma unroll
        for (int r = 0; r < 4; ++r)
            out_red[wave][q * 4 + r][dt * 16 + l] = ao[dt][r];
    }
    __syncthreads();

    #pragma unroll
    for (int i = 0; i < 4; ++i) {
        const int e = tid + 256 * i;
        const int row = e >> 6;
        const int d = e & 63;
        float s = out_red[0][row][d] + out_red[1][row][d] +
                  out_red[2][row][d] + out_red[3][row][d];
        out[(size_t)(bh * SEQ + m0 + row) * DH + d] = s;
    }
}

extern "C" void kernel_launch(void* const* d_in, const int* in_sizes, int n_in,
                              void* d_out, int out_size, void* d_ws, size_t ws_size,
                              hipStream_t stream) {
    const float* Q    = (const float*)d_in[0];
    const float* K    = (const float*)d_in[1];
    const float* V    = (const float*)d_in[2];
    const int*   mask = (const int*)d_in[3];
    float* out   = (float*)d_out;
    float* pattn = out + (size_t)BH * SEQ * DH;   // outputs concatenated: out, p_attn

    const size_t elems = (size_t)BH * SEQ * DH;   // 8M elements
    const size_t need  = elems * sizeof(short) * 3;  // Khi + Klo + Vt = 48 MB

    dim3 grid(SEQ / MT, BH);   // 64 x 128 = 8192 blocks
    if (ws_size >= need) {
        short* Khi = (short*)d_ws;
        short* Klo = Khi + elems;
        short* Vt  = Klo + elems;
        attn_convert_kernel<<<dim3(8192), 256, 0, stream>>>(K, V, Khi, Klo, Vt);
        Attention_66889820668421_kernel<<<grid, 256, 0, stream>>>(Q, Khi, Klo, Vt,
                                                                  mask, out, pattn);
    } else {
        Attention_66889820668421_fallback<<<grid, 256, 0, stream>>>(Q, K, V, mask,
                                                                    out, pattn);
    }
}

// Round 2
// 782.072 us; speedup vs baseline: 1.2381x; 1.0084x over previous
//
#include <hip/hip_runtime.h>
#include <hip/hip_bf16.h>

#define BH 128
#define SEQ 1024
#define DH 64
#define MT 16          // query rows per block
#define NW 256         // keys per wave (QK^T chunk)
#define PSTRIDE 1032   // P_lds row stride in shorts (padded +8 to break bank conflicts)

typedef __attribute__((ext_vector_type(8))) short short8;
typedef __attribute__((ext_vector_type(4))) float float4v;

__device__ __forceinline__ short bf16_rne(float x) {
    unsigned u = __builtin_bit_cast(unsigned, x);
    unsigned r = (u + 0x7fffu + ((u >> 16) & 1u)) >> 16;
    return (short)r;
}

// hi = truncated bf16, lo = RNE bf16 of the residual (x ~= hi + lo to ~2^-17 rel)
__device__ __forceinline__ void bf16_split(float x, short& hi, short& lo) {
    unsigned u = __builtin_bit_cast(unsigned, x);
    hi = (short)(u >> 16);
    float hf = __builtin_bit_cast(float, u & 0xffff0000u);
    float res = x - hf;
    unsigned v = __builtin_bit_cast(unsigned, res);
    lo = (short)((v + 0x7fffu + ((v >> 16) & 1u)) >> 16);
}

// ---------------------------------------------------------------------------
// Pre-pass: convert K -> (Khi, Klo) split bf16 and V -> Vt bf16, both stored
// in MFMA B-fragment order so the main kernel does pure 16B vector loads.
//
// Khi/Klo element (key, d) of head bh stored at:
//   bh*65536 + ((keyblk*2 + s)*16 + l)*32 + q*8 + j
//   where keyblk=key/16, l=key%16, s=d/32, q=(d%32)/8, j=d%8
// Vt element (d, key) of head bh stored at:
//   bh*65536 + ((d4*128 + key8)*16 + lv)*8 + j
//   where d4=d/16, lv=d%16, key8=key/8, j=key%8
// ---------------------------------------------------------------------------
__global__ __launch_bounds__(256, 4)
void attn_convert_kernel(const float* __restrict__ K, const float* __restrict__ V,
                         short* __restrict__ Khi, short* __restrict__ Klo,
                         short* __restrict__ Vt)
{
    const unsigned c = blockIdx.x * 256u + threadIdx.x;   // chunk of 8 shorts
    if (blockIdx.x < 4096) {
        // ---- K: 128 bh * 8192 chunks ----
        const int bh = c >> 13;
        const int o8 = c & 8191;
        const int q  = o8 & 3;
        const int l  = (o8 >> 2) & 15;
        const int s  = (o8 >> 6) & 1;
        const int kb = o8 >> 7;
        const float* src = K + ((size_t)bh * SEQ + kb * 16 + l) * DH + s * 32 + q * 8;
        float4v x0 = *(const float4v*)src;
        float4v x1 = *(const float4v*)(src + 4);
        short8 hi, lo;
        #pragma unroll
        for (int j = 0; j < 4; ++j) {
            short h, w;
            bf16_split(x0[j], h, w); hi[j] = h;     lo[j] = w;
            bf16_split(x1[j], h, w); hi[4 + j] = h; lo[4 + j] = w;
        }
        *(short8*)(Khi + (size_t)c * 8) = hi;
        *(short8*)(Klo + (size_t)c * 8) = lo;
    } else {
        // ---- V: 128 bh * 8192 chunks ----
        const unsigned c2 = c - 4096u * 256u;
        const int bh = c2 >> 13;
        const int o8 = c2 & 8191;
        const int lv = o8 & 15;
        const int k8 = (o8 >> 4) & 127;
        const int d4 = o8 >> 11;
        const float* src = V + ((size_t)bh * SEQ + k8 * 8) * DH + d4 * 16 + lv;
        short8 vv;
        #pragma unroll
        for (int j = 0; j < 8; ++j) vv[j] = bf16_rne(src[(size_t)j * DH]);
        *(short8*)(Vt + (size_t)c2 * 8) = vv;
    }
}

// ---------------------------------------------------------------------------
// Main attention kernel: pre-swizzled bf16 K (split) and V.
// PV is D-split: wave w computes the FULL 1024-key sum for d in [16w,16w+16)
// -> no cross-wave output reduction, no out_red LDS, 4 blocks/CU.
// ---------------------------------------------------------------------------
__global__ __launch_bounds__(256, 4)
void Attention_66889820668421_kernel(const float* __restrict__ Q,
                                     const short* __restrict__ Khi,
                                     const short* __restrict__ Klo,
                                     const short* __restrict__ Vt,
                                     const int*   __restrict__ mask,
                                     float* __restrict__ out,
                                     float* __restrict__ pattn)
{
    __shared__ short P_lds[MT * PSTRIDE];          // 33 KB: p tile, bf16
    __shared__ float red_max[4][MT];
    __shared__ float red_sum[4][MT];

    const int tid  = threadIdx.x;
    const int wave = tid >> 6;
    const int lane = tid & 63;
    const int q    = lane >> 4;     // quad 0..3
    const int l    = lane & 15;
    const int bh   = blockIdx.y;
    const int m0   = blockIdx.x * MT;
    const int nbase = wave * NW;

    // ---------------- Q fragments (split hi/lo), 2 K-steps of 32 ----------------
    short8 a_hi[2], a_lo[2];
    {
        const float* qrow = Q + (size_t)(bh * SEQ + m0 + l) * DH;
        #pragma unroll
        for (int s = 0; s < 2; ++s) {
            float4v x0 = *(const float4v*)(qrow + s * 32 + q * 8);
            float4v x1 = *(const float4v*)(qrow + s * 32 + q * 8 + 4);
            #pragma unroll
            for (int j = 0; j < 4; ++j) {
                short h, lo2;
                bf16_split(x0[j], h, lo2); a_hi[s][j] = h; a_lo[s][j] = lo2;
                bf16_split(x1[j], h, lo2); a_hi[s][4 + j] = h; a_lo[s][4 + j] = lo2;
            }
        }
    }

    const short* khb = Khi + ((size_t)bh << 16);
    const short* klb = Klo + ((size_t)bh << 16);
    const short* vtb = Vt  + ((size_t)bh << 16);

    // ---------------- QK^T: 16 tiles of 16 keys, split-precision MFMA ------------
    float4v acc[16];
    int mv[16];
    #pragma unroll
    for (int t = 0; t < 16; ++t) {
        const int kb   = (nbase >> 4) + t;
        const int off0 = kb * 1024 + l * 32 + q * 8;   // s=0 fragment
        short8 b0h = *(const short8*)(khb + off0);
        short8 b0l = *(const short8*)(klb + off0);
        short8 b1h = *(const short8*)(khb + off0 + 512);
        short8 b1l = *(const short8*)(klb + off0 + 512);
        float4v a = {0.f, 0.f, 0.f, 0.f};
        a = __builtin_amdgcn_mfma_f32_16x16x32_bf16(a_hi[0], b0h, a, 0, 0, 0);
        a = __builtin_amdgcn_mfma_f32_16x16x32_bf16(a_hi[0], b0l, a, 0, 0, 0);
        a = __builtin_amdgcn_mfma_f32_16x16x32_bf16(a_lo[0], b0h, a, 0, 0, 0);
        a = __builtin_amdgcn_mfma_f32_16x16x32_bf16(a_hi[1], b1h, a, 0, 0, 0);
        a = __builtin_amdgcn_mfma_f32_16x16x32_bf16(a_hi[1], b1l, a, 0, 0, 0);
        a = __builtin_amdgcn_mfma_f32_16x16x32_bf16(a_lo[1], b1h, a, 0, 0, 0);
        mv[t] = mask[bh * SEQ + nbase + t * 16 + l];
        acc[t] = a;
    }

    // ---------------- scale + mask + row max ----------------
    const float scale = 0.03125f;   // 1/sqrt(1024)
    float pm[4] = {-3e38f, -3e38f, -3e38f, -3e38f};
    #pragma unroll
    for (int t = 0; t < 16; ++t) {
        const bool ok = (mv[t] != 0);
        #pragma unroll
        for (int r = 0; r < 4; ++r) {
            float s = ok ? acc[t][r] * scale : -1e9f;
            acc[t][r] = s;
            pm[r] = fmaxf(pm[r], s);
        }
    }
    #pragma unroll
    for (int off = 1; off < 16; off <<= 1) {
        #pragma unroll
        for (int r = 0; r < 4; ++r)
            pm[r] = fmaxf(pm[r], __shfl_xor(pm[r], off));
    }
    if (l == 0) {
        #pragma unroll
        for (int r = 0; r < 4; ++r) red_max[wave][q * 4 + r] = pm[r];
    }
    __syncthreads();

    float rm[4];
    #pragma unroll
    for (int r = 0; r < 4; ++r) {
        const int row = q * 4 + r;
        rm[r] = fmaxf(fmaxf(red_max[0][row], red_max[1][row]),
                      fmaxf(red_max[2][row], red_max[3][row]));
    }

    // ---------------- exp + row sum ----------------
    float ps[4] = {0.f, 0.f, 0.f, 0.f};
    #pragma unroll
    for (int t = 0; t < 16; ++t) {
        #pragma unroll
        for (int r = 0; r < 4; ++r) {
            float e = __expf(acc[t][r] - rm[r]);
            acc[t][r] = e;
            ps[r] += e;
        }
    }
    #pragma unroll
    for (int off = 1; off < 16; off <<= 1) {
        #pragma unroll
        for (int r = 0; r < 4; ++r)
            ps[r] += __shfl_xor(ps[r], off);
    }
    if (l == 0) {
        #pragma unroll
        for (int r = 0; r < 4; ++r) red_sum[wave][q * 4 + r] = ps[r];
    }
    __syncthreads();

    float inv[4];
    #pragma unroll
    for (int r = 0; r < 4; ++r) {
        const int row = q * 4 + r;
        inv[r] = 1.0f / (red_sum[0][row] + red_sum[1][row] +
                         red_sum[2][row] + red_sum[3][row]);
    }

    // ---------------- normalize, write p (fp32 global, streaming) + P_lds -------
    float* prow = pattn + ((size_t)bh * SEQ + m0) * SEQ;
    #pragma unroll
    for (int t = 0; t < 16; ++t) {
        const int col = nbase + t * 16 + l;
        #pragma unroll
        for (int r = 0; r < 4; ++r) {
            const int row = q * 4 + r;
            float p = acc[t][r] * inv[r];
            __builtin_nontemporal_store(p, &prow[(size_t)row * SEQ + col]);
            P_lds[row * PSTRIDE + col] = bf16_rne(p);
        }
    }
    __syncthreads();

    // ---------------- PV, D-split: wave w -> d in [16w, 16w+16) ------------------
    // A-fragment: pa[j] = P[row=l][key0 + q*8 + j]   (ds_read_b128, conflict-free)
    // B-fragment: vb[j] = V[key0 + q*8 + j][16w + l] (pre-swizzled, 16B load)
    float4v ao = {0.f, 0.f, 0.f, 0.f};
    const short* vwb = vtb + (size_t)wave * 16384;   // wave's d-slice of Vt
    #pragma unroll 4
    for (int step = 0; step < 32; ++step) {
        const int key0 = step * 32;
        short8 pa = *(const short8*)&P_lds[l * PSTRIDE + key0 + q * 8];
        short8 vb = *(const short8*)(vwb + (((size_t)((key0 >> 3) + q)) * 16 + l) * 8);
        ao = __builtin_amdgcn_mfma_f32_16x16x32_bf16(pa, vb, ao, 0, 0, 0);
    }

    // ---------------- direct store: out[row][16*wave + l] ------------------------
    const int d = wave * 16 + l;
    #pragma unroll
    for (int r = 0; r < 4; ++r) {
        const int row = q * 4 + r;
        __builtin_nontemporal_store(ao[r], &out[(size_t)(bh * SEQ + m0 + row) * DH + d]);
    }
}

// ---------------------------------------------------------------------------
// Fallback (no-workspace path) — previous session's verified kernel.
// ---------------------------------------------------------------------------
__global__ __launch_bounds__(256, 2)
void Attention_66889820668421_fallback(const float* __restrict__ Q,
                                       const float* __restrict__ K,
                                       const float* __restrict__ V,
                                       const int*   __restrict__ mask,
                                       float* __restrict__ out,
                                       float* __restrict__ pattn)
{
    __shared__ short P_lds[MT * PSTRIDE];
    __shared__ float out_red[4][MT][DH];
    __shared__ float red_max[4][MT];
    __shared__ float red_sum[4][MT];

    const int tid  = threadIdx.x;
    const int wave = tid >> 6;
    const int lane = tid & 63;
    const int q    = lane >> 4;
    const int l    = lane & 15;
    const int bh   = blockIdx.y;
    const int m0   = blockIdx.x * MT;
    const int nbase = wave * NW;

    short8 a_hi[2], a_lo[2];
    {
        const float* qrow = Q + (size_t)(bh * SEQ + m0 + l) * DH;
        #pragma unroll
        for (int s = 0; s < 2; ++s) {
            float4v x0 = *(const float4v*)(qrow + s * 32 + q * 8);
            float4v x1 = *(const float4v*)(qrow + s * 32 + q * 8 + 4);
            #pragma unroll
            for (int j = 0; j < 4; ++j) {
                short h, lo2;
                bf16_split(x0[j], h, lo2); a_hi[s][j] = h; a_lo[s][j] = lo2;
                bf16_split(x1[j], h, lo2); a_hi[s][4 + j] = h; a_lo[s][4 + j] = lo2;
            }
        }
    }

    float4v acc[16];
    int mv[16];
    #pragma unroll
    for (int t = 0; t < 16; ++t) {
        const int key = nbase + t * 16 + l;
        const float* krow = K + (size_t)(bh * SEQ + key) * DH;
        float4v a = {0.f, 0.f, 0.f, 0.f};
        #pragma unroll
        for (int s = 0; s < 2; ++s) {
            float4v x0 = *(const float4v*)(krow + s * 32 + q * 8);
            float4v x1 = *(const float4v*)(krow + s * 32 + q * 8 + 4);
            short8 bhh, bll;
            #pragma unroll
            for (int j = 0; j < 4; ++j) {
                short h, lo2;
                bf16_split(x0[j], h, lo2); bhh[j] = h; bll[j] = lo2;
                bf16_split(x1[j], h, lo2); bhh[4 + j] = h; bll[4 + j] = lo2;
            }
            a = __builtin_amdgcn_mfma_f32_16x16x32_bf16(a_hi[s], bhh, a, 0, 0, 0);
            a = __builtin_amdgcn_mfma_f32_16x16x32_bf16(a_hi[s], bll, a, 0, 0, 0);
            a = __builtin_amdgcn_mfma_f32_16x16x32_bf16(a_lo[s], bhh, a, 0, 0, 0);
        }
        mv[t] = mask[bh * SEQ + nbase + t * 16 + l];
        acc[t] = a;
    }

    const float scale = 0.03125f;
    float pm[4] = {-3e38f, -3e38f, -3e38f, -3e38f};
    #pragma unroll
    for (int t = 0; t < 16; ++t) {
        const bool ok = (mv[t] != 0);
        #pragma unroll
        for (int r = 0; r < 4; ++r) {
            float s = ok ? acc[t][r] * scale : -1e9f;
            acc[t][r] = s;
            pm[r] = fmaxf(pm[r], s);
        }
    }
    #pragma unroll
    for (int off = 1; off < 16; off <<= 1) {
        #pragma unroll
        for (int r = 0; r < 4; ++r)
            pm[r] = fmaxf(pm[r], __shfl_xor(pm[r], off));
    }
    if (l == 0) {
        #pragma unroll
        for (int r = 0; r < 4; ++r) red_max[wave][q * 4 + r] = pm[r];
    }
    __syncthreads();

    float rm[4];
    #pragma unroll
    for (int r = 0; r < 4; ++r) {
        const int row = q * 4 + r;
        rm[r] = fmaxf(fmaxf(red_max[0][row], red_max[1][row]),
                      fmaxf(red_max[2][row], red_max[3][row]));
    }

    float ps[4] = {0.f, 0.f, 0.f, 0.f};
    #pragma unroll
    for (int t = 0; t < 16; ++t) {
        #pragma unroll
        for (int r = 0; r < 4; ++r) {
            float e = __expf(acc[t][r] - rm[r]);
            acc[t][r] = e;
            ps[r] += e;
        }
    }
    #pragma unroll
    for (int off = 1; off < 16; off <<= 1) {
        #pragma unroll
        for (int r = 0; r < 4; ++r)
            ps[r] += __shfl_xor(ps[r], off);
    }
    if (l == 0) {
        #pragma unroll
        for (int r = 0; r < 4; ++r) red_sum[wave][q * 4 + r] = ps[r];
    }
    __syncthreads();

    float inv[4];
    #pragma unroll
    for (int r = 0; r < 4; ++r) {
        const int row = q * 4 + r;
        inv[r] = 1.0f / (red_sum[0][row] + red_sum[1][row] +
                         red_sum[2][row] + red_sum[3][row]);
    }

    float* prow = pattn + ((size_t)bh * SEQ + m0) * SEQ;
    #pragma unroll
    for (int t = 0; t < 16; ++t) {
        const int col = nbase + t * 16 + l;
        #pragma unroll
        for (int r = 0; r < 4; ++r) {
            const int row = q * 4 + r;
            float p = acc[t][r] * inv[r];
            prow[(size_t)row * SEQ + col] = p;
            P_lds[row * PSTRIDE + col] = bf16_rne(p);
        }
    }
    __syncthreads();

    float4v ao[4];
    #pragma unroll
    for (int dt = 0; dt < 4; ++dt) ao[dt] = (float4v){0.f, 0.f, 0.f, 0.f};

    #pragma unroll 2
    for (int step = 0; step < 8; ++step) {
        const int key0 = nbase + step * 32;
        short8 pa = *(const short8*)&P_lds[l * PSTRIDE + key0 + q * 8];
        const float* vbase = V + (size_t)(bh * SEQ + key0 + q * 8) * DH + l;
        #pragma unroll
        for (int dt = 0; dt < 4; ++dt) {
            short8 vb;
            #pragma unroll
            for (int j = 0; j < 8; ++j)
                vb[j] = bf16_rne(vbase[(size_t)j * DH + dt * 16]);
            ao[dt] = __builtin_amdgcn_mfma_f32_16x16x32_bf16(pa, vb, ao[dt], 0, 0, 0);
        }
    }

    #pragma unroll
    for (int dt = 0; dt < 4; ++dt) {
        #pragma unroll
        for (int r = 0; r < 4; ++r)
            out_red[wave][q * 4 + r][dt * 16 + l] = ao[dt][r];
    }
    __syncthreads();

    #pragma unroll
    for (int i = 0; i < 4; ++i) {
        const int e = tid + 256 * i;
        const int row = e >> 6;
        const int d = e & 63;
        float s = out_red[0][row][d] + out_red[1][row][d] +
                  out_red[2][row][d] + out_red[3][row][d];
        out[(size_t)(bh * SEQ + m0 + row) * DH + d] = s;
    }
}

extern "C" void kernel_launch(void* const* d_in, const int* in_sizes, int n_in,
                              void* d_out, int out_size, void* d_ws, size_t ws_size,
                              hipStream_t stream) {
    const float* Q    = (const float*)d_in[0];
    const float* K    = (const float*)d_in[1];
    const float* V    = (const float*)d_in[2];
    const int*   mask = (const int*)d_in[3];
    float* out   = (float*)d_out;
    float* pattn = out + (size_t)BH * SEQ * DH;   // outputs concatenated: out, p_attn

    const size_t elems = (size_t)BH * SEQ * DH;   // 8M elements
    const size_t need  = elems * sizeof(short) * 3;  // Khi + Klo + Vt = 48 MB

    dim3 grid(SEQ / MT, BH);   // 64 x 128 = 8192 blocks
    if (ws_size >= need) {
        short* Khi = (short*)d_ws;
        short* Klo = Khi + elems;
        short* Vt  = Klo + elems;
        attn_convert_kernel<<<dim3(8192), 256, 0, stream>>>(K, V, Khi, Klo, Vt);
        Attention_66889820668421_kernel<<<grid, 256, 0, stream>>>(Q, Khi, Klo, Vt,
                                                                  mask, out, pattn);
    } else {
        Attention_66889820668421_fallback<<<grid, 256, 0, stream>>>(Q, K, V, mask,
                                                                    out, pattn);
    }
}